// Round 1
// baseline (291.334 us; speedup 1.0000x reference)
//
#include <hip/hip_runtime.h>
#include <stdint.h>

#define N_NODES 4096
#define F_DIM   256
#define BATCH   8

typedef __attribute__((ext_vector_type(8))) __bf16 bf16x8;
typedef __attribute__((ext_vector_type(4))) float  f32x4;

typedef const __attribute__((address_space(1))) void* gas1_t;
typedef __attribute__((address_space(3))) void*       las3_t;

__device__ __forceinline__ void stage16(const void* g, void* l) {
  // async global->LDS, 16B per lane; LDS dest is wave-uniform base + lane*16
  __builtin_amdgcn_global_load_lds((gas1_t)g, (las3_t)l, 16, 0, 0);
}

__device__ __forceinline__ unsigned short f2bf(float f) {
  union { float f; uint32_t u; } v; v.f = f;
  uint32_t u = v.u;
  return (unsigned short)((u + 0x7FFFu + ((u >> 16) & 1u)) >> 16); // RTNE
}

// ---------------- degree: D[i] = sum_j relu(0.5*(A[i,j]+A[j,i])) ----------------
__global__ __launch_bounds__(256) void k_deg(const float* __restrict__ A,
                                             float* __restrict__ D) {
  __shared__ float L1[64][65];
  __shared__ float L2[64][65];
  __shared__ float P[4][64];
  int t = threadIdx.x;
  int i0 = blockIdx.y * 64;
  int j0 = blockIdx.x * 64;
  for (int it = 0; it < 16; ++it) {
    int idx = it * 256 + t;
    int r = idx >> 6, c = idx & 63;
    L1[r][c] = A[(size_t)(i0 + r) * N_NODES + (j0 + c)];
    L2[c][r] = A[(size_t)(j0 + r) * N_NODES + (i0 + c)]; // L2[x][y] = A[j0+y][i0+x]... stored so L2[r][c]=A[j0+c][i0+r]
  }
  __syncthreads();
  int r = t & 63, seg = t >> 6;
  float s = 0.f;
  for (int c = seg * 16; c < seg * 16 + 16; ++c) {
    float v = 0.5f * (L1[r][c] + L2[r][c]);
    s += v > 0.f ? v : 0.f;
  }
  P[seg][r] = s;
  __syncthreads();
  if (t < 64) {
    float d = P[0][t] + P[1][t] + P[2][t] + P[3][t];
    atomicAdd(&D[i0 + t], d);
  }
}

__global__ void k_dinv(const float* __restrict__ D, float* __restrict__ dinv) {
  int i = blockIdx.x * blockDim.x + threadIdx.x;
  if (i < N_NODES) {
    float d = D[i];
    dinv[i] = d > 0.f ? 1.0f / sqrtf(d) : 0.f;
  }
}

// Mb[i,j] = bf16( dinv[i]*dinv[j]*relu(0.5*(A[i,j]+A[j,i])) )
__global__ __launch_bounds__(256) void k_build_Mb(const float* __restrict__ A,
                                                  const float* __restrict__ dinv,
                                                  unsigned short* __restrict__ Mb) {
  __shared__ float L1[64][65];
  __shared__ float L2[64][65];
  int t = threadIdx.x;
  int i0 = blockIdx.y * 64, j0 = blockIdx.x * 64;
  for (int it = 0; it < 16; ++it) {
    int idx = it * 256 + t;
    int r = idx >> 6, c = idx & 63;
    L1[r][c] = A[(size_t)(i0 + r) * N_NODES + (j0 + c)];
    L2[c][r] = A[(size_t)(j0 + r) * N_NODES + (i0 + c)];
  }
  __syncthreads();
  for (int it = 0; it < 16; ++it) {
    int idx = it * 256 + t;
    int r = idx >> 6, c = idx & 63;
    float v = 0.5f * (L1[r][c] + L2[r][c]);
    v = v > 0.f ? v : 0.f;
    v *= dinv[i0 + r] * dinv[j0 + c];
    Mb[(size_t)(i0 + r) * N_NODES + (j0 + c)] = f2bf(v);
  }
}

__global__ void k_cvt_H(const float4* __restrict__ H, ushort4* __restrict__ Hb, int n4) {
  int i = blockIdx.x * blockDim.x + threadIdx.x;
  if (i < n4) {
    float4 v = H[i];
    ushort4 o;
    o.x = f2bf(v.x); o.y = f2bf(v.y); o.z = f2bf(v.z); o.w = f2bf(v.w);
    Hb[i] = o;
  }
}

// Wt[o][f] = bf16(W[f][o])  (B-operand [N][K] layout for GEMM1)
__global__ void k_cvt_W(const float* __restrict__ W, unsigned short* __restrict__ Wt) {
  int t = blockIdx.x * blockDim.x + threadIdx.x;
  int f = t >> 8, o = t & 255;
  Wt[o * 256 + f] = f2bf(W[t]);
}

// Gt[b*256+o][m] = bf16(HW[b,m,o])   (B-operand [N][K] layout for GEMM2)
__global__ __launch_bounds__(256) void k_build_Gt(const float* __restrict__ HW,
                                                  unsigned short* __restrict__ Gt) {
  __shared__ float L[64][65];
  int t = threadIdx.x;
  int m0 = blockIdx.x * 64;
  int o0 = (blockIdx.y & 3) * 64;
  int b  = blockIdx.y >> 2;
  const float* src = HW + (size_t)b * N_NODES * F_DIM;
  for (int it = 0; it < 16; ++it) {
    int idx = it * 256 + t;
    int rm = idx >> 6, co = idx & 63;
    L[co][rm] = src[(size_t)(m0 + rm) * F_DIM + (o0 + co)];
  }
  __syncthreads();
  for (int it = 0; it < 16; ++it) {
    int idx = it * 256 + t;
    int ro = idx >> 6, cm = idx & 63;
    Gt[((size_t)(b * 256 + o0 + ro)) * N_NODES + (m0 + cm)] = f2bf(L[ro][cm]);
  }
}

// ---------------- MFMA GEMM: C[row][col] = sum_k Amat[row][k] * Bt[col][k] ----------------
// 128x128 block tile, BK=32, 4 waves each 64x64 (4x4 of 16x16x32 MFMA).
// MODE 0: Cout[row*ldC+col] = acc
// MODE 1: b=col>>8, o=col&255; idx=((b*4096+row)*256+o); Out[idx]=relu(HW[idx]-acc)
template <int MODE>
__global__ __launch_bounds__(256) void k_gemm(const unsigned short* __restrict__ Amat,
                                              const unsigned short* __restrict__ Bt,
                                              int K,
                                              float* __restrict__ Cout,
                                              const float* __restrict__ HW,
                                              float* __restrict__ Out,
                                              int ldC) {
  __shared__ __align__(16) unsigned short As[128 * 32];
  __shared__ __align__(16) unsigned short Bs[128 * 32];
  int t = threadIdx.x;
  int lane = t & 63;
  int q = lane >> 4, r16 = lane & 15;
  int wave = t >> 6;
  int wm = wave >> 1, wn = wave & 1;
  int m0 = blockIdx.y * 128;
  int n0 = blockIdx.x * 128;

  const unsigned short* Abase = Amat + (size_t)m0 * K;
  const unsigned short* Bbase = Bt + (size_t)n0 * K;

  f32x4 acc[4][4];
#pragma unroll
  for (int i = 0; i < 4; ++i)
#pragma unroll
    for (int j = 0; j < 4; ++j)
      acc[i][j] = f32x4{0.f, 0.f, 0.f, 0.f};

  int idx0 = t;            // staging unit = 8 bf16 = 16B
  int idx1 = 256 + t;
  int wb0 = (t & ~63) * 8;       // wave-uniform LDS elem offset, call 0
  int wb1 = (256 + (t & ~63)) * 8;

  int kiter = K >> 5;
  for (int kt = 0; kt < kiter; ++kt) {
    int kof = kt * 32;
    stage16(Abase + (size_t)(idx0 >> 2) * K + kof + ((idx0 & 3) << 3), &As[wb0]);
    stage16(Abase + (size_t)(idx1 >> 2) * K + kof + ((idx1 & 3) << 3), &As[wb1]);
    stage16(Bbase + (size_t)(idx0 >> 2) * K + kof + ((idx0 & 3) << 3), &Bs[wb0]);
    stage16(Bbase + (size_t)(idx1 >> 2) * K + kof + ((idx1 & 3) << 3), &Bs[wb1]);
    __syncthreads();
    bf16x8 a[4], b[4];
#pragma unroll
    for (int mi = 0; mi < 4; ++mi)
      a[mi] = *(const bf16x8*)&As[(wm * 64 + mi * 16 + r16) * 32 + q * 8];
#pragma unroll
    for (int ni = 0; ni < 4; ++ni)
      b[ni] = *(const bf16x8*)&Bs[(wn * 64 + ni * 16 + r16) * 32 + q * 8];
#pragma unroll
    for (int mi = 0; mi < 4; ++mi)
#pragma unroll
      for (int ni = 0; ni < 4; ++ni)
        acc[mi][ni] = __builtin_amdgcn_mfma_f32_16x16x32_bf16(a[mi], b[ni], acc[mi][ni], 0, 0, 0);
    __syncthreads();
  }

#pragma unroll
  for (int mi = 0; mi < 4; ++mi) {
    int row = m0 + wm * 64 + mi * 16 + q * 4;
#pragma unroll
    for (int ni = 0; ni < 4; ++ni) {
      int col = n0 + wn * 64 + ni * 16 + r16;
#pragma unroll
      for (int rr = 0; rr < 4; ++rr) {
        float v = acc[mi][ni][rr];
        if (MODE == 0) {
          Cout[(size_t)(row + rr) * ldC + col] = v;
        } else {
          int b_ = col >> 8, o = col & 255;
          size_t oi = ((size_t)b_ * N_NODES + (row + rr)) * F_DIM + o;
          float hw = HW[oi];
          float u = hw - v;
          Out[oi] = u > 0.f ? u : 0.f;
        }
      }
    }
  }
}

extern "C" void kernel_launch(void* const* d_in, const int* in_sizes, int n_in,
                              void* d_out, int out_size, void* d_ws, size_t ws_size,
                              hipStream_t stream) {
  (void)in_sizes; (void)n_in; (void)out_size; (void)ws_size;
  const float* H = (const float*)d_in[0];
  const float* W = (const float*)d_in[1];
  const float* A = (const float*)d_in[2];
  float* out = (float*)d_out;

  char* ws = (char*)d_ws;
  size_t off = 0;
  auto alloc = [&](size_t bytes) {
    char* p = ws + off;
    off += (bytes + 255) & ~(size_t)255;
    return p;
  };
  float*          Dd   = (float*)alloc((size_t)N_NODES * 4);
  float*          dinv = (float*)alloc((size_t)N_NODES * 4);
  unsigned short* Mb   = (unsigned short*)alloc((size_t)N_NODES * N_NODES * 2);   // 32 MB
  unsigned short* Hb   = (unsigned short*)alloc((size_t)BATCH * N_NODES * F_DIM * 2); // 16 MB
  unsigned short* Wt   = (unsigned short*)alloc((size_t)F_DIM * F_DIM * 2);
  float*          HWf  = (float*)alloc((size_t)BATCH * N_NODES * F_DIM * 4);      // 32 MB
  unsigned short* Gt   = (unsigned short*)alloc((size_t)BATCH * F_DIM * N_NODES * 2); // 16 MB

  hipMemsetAsync(Dd, 0, N_NODES * 4, stream);
  k_deg<<<dim3(64, 64), 256, 0, stream>>>(A, Dd);
  k_dinv<<<16, 256, 0, stream>>>(Dd, dinv);
  k_build_Mb<<<dim3(64, 64), 256, 0, stream>>>(A, dinv, Mb);
  k_cvt_H<<<8192, 256, 0, stream>>>((const float4*)H, (ushort4*)Hb, 2097152);
  k_cvt_W<<<256, 256, 0, stream>>>(W, Wt);
  // GEMM1: [32768 x 256] = Hb[32768 x 256] * Wt^T ; grid (N/128, M/128)
  k_gemm<0><<<dim3(2, 256), 256, 0, stream>>>(Hb, Wt, 256, HWf, nullptr, nullptr, 256);
  k_build_Gt<<<dim3(64, 32), 256, 0, stream>>>(HWf, Gt);
  // GEMM2: T[4096 x 2048] = Mb[4096 x 4096] * Gt^T, fused epilogue -> out
  k_gemm<1><<<dim3(16, 32), 256, 0, stream>>>(Mb, Gt, 4096, nullptr, HWf, out, 0);
}

// Round 2
// 287.556 us; speedup vs baseline: 1.0131x; 1.0131x over previous
//
#include <hip/hip_runtime.h>
#include <stdint.h>

#define N_NODES 4096
#define F_DIM   256
#define BATCH   8

typedef __attribute__((ext_vector_type(8))) __bf16 bf16x8;
typedef __attribute__((ext_vector_type(4))) float  f32x4;
typedef __attribute__((ext_vector_type(8))) unsigned short u16x8;

typedef const __attribute__((address_space(1))) void* gas1_t;
typedef __attribute__((address_space(3))) void*       las3_t;

__device__ __forceinline__ void stage16(const void* g, void* l) {
  __builtin_amdgcn_global_load_lds((gas1_t)g, (las3_t)l, 16, 0, 0);
}

__device__ __forceinline__ unsigned short f2bf(float f) {
  union { float f; uint32_t u; } v; v.f = f;
  uint32_t u = v.u;
  return (unsigned short)((u + 0x7FFFu + ((u >> 16) & 1u)) >> 16); // RTNE
}
__device__ __forceinline__ float bf2f(unsigned short u) {
  union { uint32_t u; float f; } v; v.u = ((uint32_t)u) << 16;
  return v.f;
}

// ---------------- k_sym: one pass over A (triangle blocks) ----------------
// Sb[i][j] = bf16(relu(0.5*(A[i,j]+A[j,i])));  D[i] += row sums. A read ONCE.
__global__ __launch_bounds__(256) void k_sym(const float* __restrict__ A,
                                             unsigned short* __restrict__ Sb,
                                             float* __restrict__ D) {
  int bi = blockIdx.y, bj = blockIdx.x;
  if (bj < bi) return;                 // upper-triangle blocks only
  __shared__ float L1[64][65];
  __shared__ float L2[64][65];
  __shared__ float Pr[4][64];
  __shared__ float Pc[4][64];
  int t = threadIdx.x;
  int i0 = bi * 64, j0 = bj * 64;
  for (int it = 0; it < 16; ++it) {
    int idx = it * 256 + t;
    int r = idx >> 6, c = idx & 63;
    L1[r][c] = A[(size_t)(i0 + r) * N_NODES + (j0 + c)];
    L2[c][r] = A[(size_t)(j0 + r) * N_NODES + (i0 + c)]; // L2[r][c] = A[j0+c][i0+r]
  }
  __syncthreads();
  // compute relu(0.5(A+A^T)), write upper tile, per-thread column partials
  float colsum = 0.f;
  int cfix = t & 63, q = t >> 6;
  for (int it = 0; it < 16; ++it) {
    int r = it * 4 + q;
    float v = 0.5f * (L1[r][cfix] + L2[r][cfix]);
    v = v > 0.f ? v : 0.f;
    Sb[(size_t)(i0 + r) * N_NODES + (j0 + cfix)] = f2bf(v);
    colsum += v;
    L1[r][cfix] = v;                   // keep for rowsum + transposed write
  }
  Pc[q][cfix] = colsum;
  __syncthreads();
  // rowsum
  {
    int r = t & 63, seg = t >> 6;
    float s = 0.f;
    for (int c = seg * 16; c < seg * 16 + 16; ++c) s += L1[r][c];
    Pr[seg][r] = s;
  }
  __syncthreads();
  if (t < 64) {
    float d = Pr[0][t] + Pr[1][t] + Pr[2][t] + Pr[3][t];
    atomicAdd(&D[i0 + t], d);
  } else if (t < 128 && bi != bj) {
    int c = t - 64;
    float d = Pc[0][c] + Pc[1][c] + Pc[2][c] + Pc[3][c];
    atomicAdd(&D[j0 + c], d);
  }
  if (bi != bj) {                      // mirror tile (coalesced via LDS transpose)
    for (int it = 0; it < 16; ++it) {
      int idx = it * 256 + t;
      int ro = idx >> 6, co = idx & 63;
      Sb[(size_t)(j0 + ro) * N_NODES + (i0 + co)] = f2bf(L1[co][ro]);
    }
  }
}

__global__ void k_dinv(const float* __restrict__ D, float* __restrict__ dinv) {
  int i = blockIdx.x * blockDim.x + threadIdx.x;
  if (i < N_NODES) {
    float d = D[i];
    dinv[i] = d > 0.f ? 1.0f / sqrtf(d) : 0.f;
  }
}

__global__ void k_cvt_H(const float4* __restrict__ H, ushort4* __restrict__ Hb, int n4) {
  int i = blockIdx.x * blockDim.x + threadIdx.x;
  if (i < n4) {
    float4 v = H[i];
    ushort4 o;
    o.x = f2bf(v.x); o.y = f2bf(v.y); o.z = f2bf(v.z); o.w = f2bf(v.w);
    Hb[i] = o;
  }
}

__global__ void k_cvt_W(const float* __restrict__ W, unsigned short* __restrict__ Wt) {
  int t = blockIdx.x * blockDim.x + threadIdx.x;
  int f = t >> 8, o = t & 255;
  Wt[o * 256 + f] = f2bf(W[t]);
}

// ---------------- GEMM1: HW = Hb @ Wt^T; writes HWb (bf16, [m][o]) and
// Gt[b*256+o][n] = bf16(dinv[n]*HW) via LDS transpose (B-operand of GEMM2) ----
__global__ __launch_bounds__(256) void k_gemm1(const unsigned short* __restrict__ Hb,
                                               const unsigned short* __restrict__ Wt,
                                               const float* __restrict__ dinv,
                                               unsigned short* __restrict__ HWb,
                                               unsigned short* __restrict__ Gt) {
  __shared__ __align__(16) unsigned short As[128 * 32];
  __shared__ __align__(16) unsigned short Bs[128 * 32];
  __shared__ __align__(16) unsigned short T[128][136]; // T[o_local][m_local]
  int t = threadIdx.x;
  int lane = t & 63;
  int q = lane >> 4, r16 = lane & 15;
  int wave = t >> 6;
  int wm = wave >> 1, wn = wave & 1;
  int m0 = blockIdx.y * 128;
  int o0 = blockIdx.x * 128;
  const int K = 256;

  const unsigned short* Abase = Hb + (size_t)m0 * K;
  const unsigned short* Bbase = Wt + (size_t)o0 * K;

  f32x4 acc[4][4];
#pragma unroll
  for (int i = 0; i < 4; ++i)
#pragma unroll
    for (int j = 0; j < 4; ++j) acc[i][j] = f32x4{0.f, 0.f, 0.f, 0.f};

  int idx0 = t, idx1 = 256 + t;
  int wb0 = (t & ~63) * 8;
  int wb1 = (256 + (t & ~63)) * 8;

  for (int kt = 0; kt < K / 32; ++kt) {
    int kof = kt * 32;
    stage16(Abase + (size_t)(idx0 >> 2) * K + kof + ((idx0 & 3) << 3), &As[wb0]);
    stage16(Abase + (size_t)(idx1 >> 2) * K + kof + ((idx1 & 3) << 3), &As[wb1]);
    stage16(Bbase + (size_t)(idx0 >> 2) * K + kof + ((idx0 & 3) << 3), &Bs[wb0]);
    stage16(Bbase + (size_t)(idx1 >> 2) * K + kof + ((idx1 & 3) << 3), &Bs[wb1]);
    __syncthreads();
    bf16x8 a[4], b[4];
#pragma unroll
    for (int mi = 0; mi < 4; ++mi)
      a[mi] = *(const bf16x8*)&As[(wm * 64 + mi * 16 + r16) * 32 + q * 8];
#pragma unroll
    for (int ni = 0; ni < 4; ++ni)
      b[ni] = *(const bf16x8*)&Bs[(wn * 64 + ni * 16 + r16) * 32 + q * 8];
#pragma unroll
    for (int mi = 0; mi < 4; ++mi)
#pragma unroll
      for (int ni = 0; ni < 4; ++ni)
        acc[mi][ni] = __builtin_amdgcn_mfma_f32_16x16x32_bf16(a[mi], b[ni], acc[mi][ni], 0, 0, 0);
    __syncthreads();
  }

  // epilogue: HWb direct + T[o][m] for transposed Gt write
#pragma unroll
  for (int mi = 0; mi < 4; ++mi) {
    int row = wm * 64 + mi * 16 + q * 4;
#pragma unroll
    for (int ni = 0; ni < 4; ++ni) {
      int col = wn * 64 + ni * 16 + r16;
#pragma unroll
      for (int rr = 0; rr < 4; ++rr) {
        unsigned short h = f2bf(acc[mi][ni][rr]);
        HWb[(size_t)(m0 + row + rr) * F_DIM + (o0 + col)] = h;
        T[col][row + rr] = h;
      }
    }
  }
  __syncthreads();
  int b = m0 >> 12, n0 = m0 & 4095;
  for (int it = 0; it < 8; ++it) {
    int unit = it * 256 + t;
    int ro = unit >> 4;            // o_local
    int cs = (unit & 15) * 8;      // m_local chunk
    u16x8 v = *(const u16x8*)&T[ro][cs];
    u16x8 w;
#pragma unroll
    for (int j = 0; j < 8; ++j)
      w[j] = f2bf(bf2f(v[j]) * dinv[n0 + cs + j]);
    *(u16x8*)&Gt[(size_t)(b * 256 + o0 + ro) * N_NODES + n0 + cs] = w;
  }
}

// ---------------- GEMM2 (split-K partial): P[z][row][col] = Sb_rowK @ Gt_colK ----
__global__ __launch_bounds__(256) void k_gemm2(const unsigned short* __restrict__ Sb,
                                               const unsigned short* __restrict__ Gt,
                                               float* __restrict__ P, int Khalf) {
  __shared__ __align__(16) unsigned short As[128 * 32];
  __shared__ __align__(16) unsigned short Bs[128 * 32];
  int t = threadIdx.x;
  int lane = t & 63;
  int q = lane >> 4, r16 = lane & 15;
  int wave = t >> 6;
  int wm = wave >> 1, wn = wave & 1;
  int m0 = blockIdx.y * 128;
  int n0 = blockIdx.x * 128;
  int z = blockIdx.z;

  const unsigned short* Abase = Sb + (size_t)m0 * N_NODES + z * Khalf;
  const unsigned short* Bbase = Gt + (size_t)n0 * N_NODES + z * Khalf;

  f32x4 acc[4][4];
#pragma unroll
  for (int i = 0; i < 4; ++i)
#pragma unroll
    for (int j = 0; j < 4; ++j) acc[i][j] = f32x4{0.f, 0.f, 0.f, 0.f};

  int idx0 = t, idx1 = 256 + t;
  int wb0 = (t & ~63) * 8;
  int wb1 = (256 + (t & ~63)) * 8;

  for (int kt = 0; kt < (Khalf >> 5); ++kt) {
    int kof = kt * 32;
    stage16(Abase + (size_t)(idx0 >> 2) * N_NODES + kof + ((idx0 & 3) << 3), &As[wb0]);
    stage16(Abase + (size_t)(idx1 >> 2) * N_NODES + kof + ((idx1 & 3) << 3), &As[wb1]);
    stage16(Bbase + (size_t)(idx0 >> 2) * N_NODES + kof + ((idx0 & 3) << 3), &Bs[wb0]);
    stage16(Bbase + (size_t)(idx1 >> 2) * N_NODES + kof + ((idx1 & 3) << 3), &Bs[wb1]);
    __syncthreads();
    bf16x8 a[4], b[4];
#pragma unroll
    for (int mi = 0; mi < 4; ++mi)
      a[mi] = *(const bf16x8*)&As[(wm * 64 + mi * 16 + r16) * 32 + q * 8];
#pragma unroll
    for (int ni = 0; ni < 4; ++ni)
      b[ni] = *(const bf16x8*)&Bs[(wn * 64 + ni * 16 + r16) * 32 + q * 8];
#pragma unroll
    for (int mi = 0; mi < 4; ++mi)
#pragma unroll
      for (int ni = 0; ni < 4; ++ni)
        acc[mi][ni] = __builtin_amdgcn_mfma_f32_16x16x32_bf16(a[mi], b[ni], acc[mi][ni], 0, 0, 0);
    __syncthreads();
  }

  float* Pz = P + (size_t)z * (4096u * 2048u);
#pragma unroll
  for (int mi = 0; mi < 4; ++mi) {
    int row = m0 + wm * 64 + mi * 16 + q * 4;
#pragma unroll
    for (int ni = 0; ni < 4; ++ni) {
      int col = n0 + wn * 64 + ni * 16 + r16;
#pragma unroll
      for (int rr = 0; rr < 4; ++rr)
        Pz[(size_t)(row + rr) * 2048 + col] = acc[mi][ni][rr];
    }
  }
}

// ---------------- epilogue: out = relu(HW - dinv[n]*(P0(+P1))) ----------------
__global__ __launch_bounds__(256) void k_epi(const float* __restrict__ P,
                                             const unsigned short* __restrict__ HWb,
                                             const float* __restrict__ dinv,
                                             float* __restrict__ Out, int splitk) {
  int unit = blockIdx.x * 256 + threadIdx.x;   // 2M float4 units
  int col4 = unit & 511;
  int n = unit >> 9;
  int b = col4 >> 6;
  int o4 = col4 & 63;
  size_t pidx = (size_t)n * 2048 + col4 * 4;
  float4 p = *(const float4*)&P[pidx];
  if (splitk == 2) {
    float4 p2 = *(const float4*)&P[(size_t)(4096u * 2048u) + pidx];
    p.x += p2.x; p.y += p2.y; p.z += p2.z; p.w += p2.w;
  }
  float di = dinv[n];
  size_t oi = ((size_t)(b * 4096 + n)) * 256 + o4 * 4;
  ushort4 h = *(const ushort4*)&HWb[oi];
  float4 r;
  r.x = bf2f(h.x) - di * p.x;
  r.y = bf2f(h.y) - di * p.y;
  r.z = bf2f(h.z) - di * p.z;
  r.w = bf2f(h.w) - di * p.w;
  r.x = r.x > 0.f ? r.x : 0.f;
  r.y = r.y > 0.f ? r.y : 0.f;
  r.z = r.z > 0.f ? r.z : 0.f;
  r.w = r.w > 0.f ? r.w : 0.f;
  *(float4*)&Out[oi] = r;
}

extern "C" void kernel_launch(void* const* d_in, const int* in_sizes, int n_in,
                              void* d_out, int out_size, void* d_ws, size_t ws_size,
                              hipStream_t stream) {
  (void)in_sizes; (void)n_in; (void)out_size;
  const float* H = (const float*)d_in[0];
  const float* W = (const float*)d_in[1];
  const float* A = (const float*)d_in[2];
  float* out = (float*)d_out;

  char* ws = (char*)d_ws;
  size_t off = 0;
  auto alloc = [&](size_t bytes) {
    char* p = ws + off;
    off += (bytes + 255) & ~(size_t)255;
    return p;
  };
  float*          Dd   = (float*)alloc((size_t)N_NODES * 4);
  float*          dinv = (float*)alloc((size_t)N_NODES * 4);
  unsigned short* Sb   = (unsigned short*)alloc((size_t)N_NODES * N_NODES * 2);        // 32 MB
  unsigned short* HWb  = (unsigned short*)alloc((size_t)BATCH * N_NODES * F_DIM * 2);  // 16 MB
  unsigned short* Gt   = (unsigned short*)alloc((size_t)BATCH * F_DIM * N_NODES * 2);  // 16 MB
  unsigned short* Wt   = (unsigned short*)alloc((size_t)F_DIM * F_DIM * 2);
  // tail: Hb (16 MB, dead after GEMM1) aliased by split-K partials P
  char* tail = ws + off;
  unsigned short* Hb = (unsigned short*)tail;
  float*          P  = (float*)tail;
  size_t partial_bytes = (size_t)4096u * 2048u * 4;   // 32 MB per K-half
  int splitk = (ws_size >= off + 2 * partial_bytes) ? 2 : 1;

  hipMemsetAsync(Dd, 0, N_NODES * 4, stream);
  k_sym<<<dim3(64, 64), 256, 0, stream>>>(A, Sb, Dd);
  k_dinv<<<16, 256, 0, stream>>>(Dd, dinv);
  k_cvt_H<<<8192, 256, 0, stream>>>((const float4*)H, (ushort4*)Hb, 2097152);
  k_cvt_W<<<256, 256, 0, stream>>>(W, Wt);
  k_gemm1<<<dim3(2, 256), 256, 0, stream>>>(Hb, Wt, dinv, HWb, Gt);
  k_gemm2<<<dim3(16, 32, splitk), 256, 0, stream>>>(Sb, Gt, P, N_NODES / splitk);
  k_epi<<<8192, 256, 0, stream>>>(P, HWb, dinv, out, splitk);
}

// Round 3
// 266.842 us; speedup vs baseline: 1.0918x; 1.0776x over previous
//
#include <hip/hip_runtime.h>
#include <stdint.h>

#define N_NODES 4096
#define F_DIM   256
#define BATCH   8

typedef __attribute__((ext_vector_type(8))) __bf16 bf16x8;
typedef __attribute__((ext_vector_type(4))) float  f32x4;
typedef __attribute__((ext_vector_type(8))) unsigned short u16x8;

typedef const __attribute__((address_space(1))) void* gas1_t;
typedef __attribute__((address_space(3))) void*       las3_t;

__device__ __forceinline__ void stage16(const void* g, void* l) {
  __builtin_amdgcn_global_load_lds((gas1_t)g, (las3_t)l, 16, 0, 0);
}

__device__ __forceinline__ unsigned short f2bf(float f) {
  union { float f; uint32_t u; } v; v.f = f;
  uint32_t u = v.u;
  return (unsigned short)((u + 0x7FFFu + ((u >> 16) & 1u)) >> 16); // RTNE
}
__device__ __forceinline__ float bf2f(unsigned short u) {
  union { uint32_t u; float f; } v; v.u = ((uint32_t)u) << 16;
  return v.f;
}

// ---------------- k_sym: one pass over A (triangle blocks) ----------------
// Sb[i][j] = bf16(relu(0.5*(A[i,j]+A[j,i])));  D[i] += row sums. A read ONCE.
__global__ __launch_bounds__(256) void k_sym(const float* __restrict__ A,
                                             unsigned short* __restrict__ Sb,
                                             float* __restrict__ D) {
  int bi = blockIdx.y, bj = blockIdx.x;
  if (bj < bi) return;                 // upper-triangle blocks only (block-uniform)
  __shared__ float L1[64][65];
  __shared__ float L2[64][65];
  __shared__ float Pr[4][64];
  __shared__ float Pc[4][64];
  int t = threadIdx.x;
  int i0 = bi * 64, j0 = bj * 64;
  for (int it = 0; it < 16; ++it) {
    int idx = it * 256 + t;
    int r = idx >> 6, c = idx & 63;
    L1[r][c] = A[(size_t)(i0 + r) * N_NODES + (j0 + c)];
    L2[c][r] = A[(size_t)(j0 + r) * N_NODES + (i0 + c)]; // L2[r][c] = A[j0+c][i0+r]
  }
  __syncthreads();
  float colsum = 0.f;
  int cfix = t & 63, q = t >> 6;
  for (int it = 0; it < 16; ++it) {
    int r = it * 4 + q;
    float v = 0.5f * (L1[r][cfix] + L2[r][cfix]);
    v = v > 0.f ? v : 0.f;
    Sb[(size_t)(i0 + r) * N_NODES + (j0 + cfix)] = f2bf(v);
    colsum += v;
    L1[r][cfix] = v;
  }
  Pc[q][cfix] = colsum;
  __syncthreads();
  {
    int r = t & 63, seg = t >> 6;
    float s = 0.f;
    for (int c = seg * 16; c < seg * 16 + 16; ++c) s += L1[r][c];
    Pr[seg][r] = s;
  }
  __syncthreads();
  if (t < 64) {
    float d = Pr[0][t] + Pr[1][t] + Pr[2][t] + Pr[3][t];
    atomicAdd(&D[i0 + t], d);
  } else if (t < 128 && bi != bj) {
    int c = t - 64;
    float d = Pc[0][c] + Pc[1][c] + Pc[2][c] + Pc[3][c];
    atomicAdd(&D[j0 + c], d);
  }
  if (bi != bj) {
    for (int it = 0; it < 16; ++it) {
      int idx = it * 256 + t;
      int ro = idx >> 6, co = idx & 63;
      Sb[(size_t)(j0 + ro) * N_NODES + (i0 + co)] = f2bf(L1[co][ro]);
    }
  }
}

__global__ void k_dinv(const float* __restrict__ D, float* __restrict__ dinv) {
  int i = blockIdx.x * blockDim.x + threadIdx.x;
  if (i < N_NODES) {
    float d = D[i];
    dinv[i] = d > 0.f ? 1.0f / sqrtf(d) : 0.f;
  }
}

// merged H-cast + W-transpose-cast (one launch)
__global__ __launch_bounds__(256) void k_cvt(const float4* __restrict__ H,
                                             ushort4* __restrict__ Hb,
                                             const float* __restrict__ W,
                                             unsigned short* __restrict__ Wt) {
  int bid = blockIdx.x;
  if (bid < 8192) {
    int i = bid * 256 + threadIdx.x;
    float4 v = H[i];
    ushort4 o;
    o.x = f2bf(v.x); o.y = f2bf(v.y); o.z = f2bf(v.z); o.w = f2bf(v.w);
    Hb[i] = o;
  } else {
    int t = (bid - 8192) * 256 + threadIdx.x;   // 65536 elems
    int f = t >> 8, o = t & 255;
    Wt[o * 256 + f] = f2bf(W[t]);
  }
}

// ---------------- GEMM1: HW = Hb @ Wt^T; writes HWb (bf16) and
// Gt[b*256+o][n] = bf16(dinv[n]*HW) via LDS transpose ----
__global__ __launch_bounds__(256) void k_gemm1(const unsigned short* __restrict__ Hb,
                                               const unsigned short* __restrict__ Wt,
                                               const float* __restrict__ dinv,
                                               unsigned short* __restrict__ HWb,
                                               unsigned short* __restrict__ Gt) {
  __shared__ __align__(16) unsigned short As[128 * 32];
  __shared__ __align__(16) unsigned short Bs[128 * 32];
  __shared__ __align__(16) unsigned short T[128][136];
  int t = threadIdx.x;
  int lane = t & 63;
  int q = lane >> 4, r16 = lane & 15;
  int wave = t >> 6;
  int wm = wave >> 1, wn = wave & 1;
  int m0 = blockIdx.y * 128;
  int o0 = blockIdx.x * 128;
  const int K = 256;

  const unsigned short* Abase = Hb + (size_t)m0 * K;
  const unsigned short* Bbase = Wt + (size_t)o0 * K;

  f32x4 acc[4][4];
#pragma unroll
  for (int i = 0; i < 4; ++i)
#pragma unroll
    for (int j = 0; j < 4; ++j) acc[i][j] = f32x4{0.f, 0.f, 0.f, 0.f};

  int idx0 = t, idx1 = 256 + t;
  int wb0 = (t & ~63) * 8;
  int wb1 = (256 + (t & ~63)) * 8;

  for (int kt = 0; kt < K / 32; ++kt) {
    int kof = kt * 32;
    stage16(Abase + (size_t)(idx0 >> 2) * K + kof + ((idx0 & 3) << 3), &As[wb0]);
    stage16(Abase + (size_t)(idx1 >> 2) * K + kof + ((idx1 & 3) << 3), &As[wb1]);
    stage16(Bbase + (size_t)(idx0 >> 2) * K + kof + ((idx0 & 3) << 3), &Bs[wb0]);
    stage16(Bbase + (size_t)(idx1 >> 2) * K + kof + ((idx1 & 3) << 3), &Bs[wb1]);
    __syncthreads();
    bf16x8 a[4], b[4];
#pragma unroll
    for (int mi = 0; mi < 4; ++mi)
      a[mi] = *(const bf16x8*)&As[(wm * 64 + mi * 16 + r16) * 32 + q * 8];
#pragma unroll
    for (int ni = 0; ni < 4; ++ni)
      b[ni] = *(const bf16x8*)&Bs[(wn * 64 + ni * 16 + r16) * 32 + q * 8];
#pragma unroll
    for (int mi = 0; mi < 4; ++mi)
#pragma unroll
      for (int ni = 0; ni < 4; ++ni)
        acc[mi][ni] = __builtin_amdgcn_mfma_f32_16x16x32_bf16(a[mi], b[ni], acc[mi][ni], 0, 0, 0);
    __syncthreads();
  }

#pragma unroll
  for (int mi = 0; mi < 4; ++mi) {
    int row = wm * 64 + mi * 16 + q * 4;
#pragma unroll
    for (int ni = 0; ni < 4; ++ni) {
      int col = wn * 64 + ni * 16 + r16;
#pragma unroll
      for (int rr = 0; rr < 4; ++rr) {
        unsigned short h = f2bf(acc[mi][ni][rr]);
        HWb[(size_t)(m0 + row + rr) * F_DIM + (o0 + col)] = h;
        T[col][row + rr] = h;
      }
    }
  }
  __syncthreads();
  int b = m0 >> 12, n0 = m0 & 4095;
  for (int it = 0; it < 8; ++it) {
    int unit = it * 256 + t;
    int ro = unit >> 4;
    int cs = (unit & 15) * 8;
    u16x8 v = *(const u16x8*)&T[ro][cs];
    u16x8 w;
#pragma unroll
    for (int j = 0; j < 8; ++j)
      w[j] = f2bf(bf2f(v[j]) * dinv[n0 + cs + j]);
    *(u16x8*)&Gt[(size_t)(b * 256 + o0 + ro) * N_NODES + n0 + cs] = w;
  }
}

// ---------------- GEMM2: double-buffered LDS, 1 barrier/kt, fused epilogue ----
// out[b,row,o] = relu( HW[b,row,o] - dinv[row] * sum_m Sb[row,m]*Gt[col][m] )
__global__ __launch_bounds__(256) void k_gemm2(const unsigned short* __restrict__ Sb,
                                               const unsigned short* __restrict__ Gt,
                                               const unsigned short* __restrict__ HWb,
                                               const float* __restrict__ dinv,
                                               float* __restrict__ Out) {
  __shared__ __align__(16) unsigned short As[2][128 * 32];
  __shared__ __align__(16) unsigned short Bs[2][128 * 32];
  const int K = N_NODES;
  int t = threadIdx.x;
  int lane = t & 63;
  int q = lane >> 4, r16 = lane & 15;
  int wave = t >> 6;
  int wm = wave >> 1, wn = wave & 1;
  int m0 = blockIdx.y * 128;
  int n0 = blockIdx.x * 128;

  const unsigned short* Abase = Sb + (size_t)m0 * K;
  const unsigned short* Bbase = Gt + (size_t)n0 * K;

  f32x4 acc[4][4];
#pragma unroll
  for (int i = 0; i < 4; ++i)
#pragma unroll
    for (int j = 0; j < 4; ++j) acc[i][j] = f32x4{0.f, 0.f, 0.f, 0.f};

  int idx0 = t, idx1 = 256 + t;
  int wb0 = (t & ~63) * 8;
  int wb1 = (256 + (t & ~63)) * 8;
  size_t ga0 = (size_t)(idx0 >> 2) * K + ((idx0 & 3) << 3);
  size_t ga1 = (size_t)(idx1 >> 2) * K + ((idx1 & 3) << 3);

#define STG(kt, bb)                                        \
  {                                                        \
    int kof = (kt) * 32;                                   \
    stage16(Abase + ga0 + kof, &As[bb][wb0]);              \
    stage16(Abase + ga1 + kof, &As[bb][wb1]);              \
    stage16(Bbase + ga0 + kof, &Bs[bb][wb0]);              \
    stage16(Bbase + ga1 + kof, &Bs[bb][wb1]);              \
  }

  STG(0, 0)
  for (int kt = 0; kt < K / 32; ++kt) {
    int cur = kt & 1;
    __syncthreads();                 // drains stage(kt); frees buf cur^1 for prefetch
    if (kt + 1 < K / 32) STG(kt + 1, cur ^ 1)   // in flight across the MFMA block
    bf16x8 a[4], b[4];
#pragma unroll
    for (int mi = 0; mi < 4; ++mi)
      a[mi] = *(const bf16x8*)&As[cur][(wm * 64 + mi * 16 + r16) * 32 + q * 8];
#pragma unroll
    for (int ni = 0; ni < 4; ++ni)
      b[ni] = *(const bf16x8*)&Bs[cur][(wn * 64 + ni * 16 + r16) * 32 + q * 8];
#pragma unroll
    for (int mi = 0; mi < 4; ++mi)
#pragma unroll
      for (int ni = 0; ni < 4; ++ni)
        acc[mi][ni] = __builtin_amdgcn_mfma_f32_16x16x32_bf16(a[mi], b[ni], acc[mi][ni], 0, 0, 0);
  }
#undef STG

  // fused epilogue: out = relu(HW - dinv[row]*acc)
#pragma unroll
  for (int mi = 0; mi < 4; ++mi) {
    int row = m0 + wm * 64 + mi * 16 + q * 4;
    float di[4];
#pragma unroll
    for (int rr = 0; rr < 4; ++rr) di[rr] = dinv[row + rr];
#pragma unroll
    for (int ni = 0; ni < 4; ++ni) {
      int col = n0 + wn * 64 + ni * 16 + r16;
      int b_ = col >> 8, o = col & 255;
#pragma unroll
      for (int rr = 0; rr < 4; ++rr) {
        size_t oi = ((size_t)b_ * N_NODES + (row + rr)) * F_DIM + o;
        float u = bf2f(HWb[oi]) - di[rr] * acc[mi][ni][rr];
        Out[oi] = u > 0.f ? u : 0.f;
      }
    }
  }
}

extern "C" void kernel_launch(void* const* d_in, const int* in_sizes, int n_in,
                              void* d_out, int out_size, void* d_ws, size_t ws_size,
                              hipStream_t stream) {
  (void)in_sizes; (void)n_in; (void)out_size; (void)ws_size;
  const float* H = (const float*)d_in[0];
  const float* W = (const float*)d_in[1];
  const float* A = (const float*)d_in[2];
  float* out = (float*)d_out;

  char* ws = (char*)d_ws;
  size_t off = 0;
  auto alloc = [&](size_t bytes) {
    char* p = ws + off;
    off += (bytes + 255) & ~(size_t)255;
    return p;
  };
  float*          Dd   = (float*)alloc((size_t)N_NODES * 4);
  float*          dinv = (float*)alloc((size_t)N_NODES * 4);
  unsigned short* Sb   = (unsigned short*)alloc((size_t)N_NODES * N_NODES * 2);        // 32 MB
  unsigned short* HWb  = (unsigned short*)alloc((size_t)BATCH * N_NODES * F_DIM * 2);  // 16 MB
  unsigned short* Gt   = (unsigned short*)alloc((size_t)BATCH * F_DIM * N_NODES * 2);  // 16 MB
  unsigned short* Wt   = (unsigned short*)alloc((size_t)F_DIM * F_DIM * 2);
  unsigned short* Hb   = (unsigned short*)alloc((size_t)BATCH * N_NODES * F_DIM * 2);  // 16 MB

  hipMemsetAsync(Dd, 0, N_NODES * 4, stream);
  k_sym<<<dim3(64, 64), 256, 0, stream>>>(A, Sb, Dd);
  k_dinv<<<16, 256, 0, stream>>>(Dd, dinv);
  k_cvt<<<8448, 256, 0, stream>>>((const float4*)H, (ushort4*)Hb, W, Wt);
  k_gemm1<<<dim3(2, 256), 256, 0, stream>>>(Hb, Wt, dinv, HWb, Gt);
  k_gemm2<<<dim3(16, 32), 256, 0, stream>>>(Sb, Gt, HWb, dinv, out);
}

// Round 4
// 260.015 us; speedup vs baseline: 1.1205x; 1.0263x over previous
//
#include <hip/hip_runtime.h>
#include <stdint.h>

#define N_NODES 4096
#define F_DIM   256
#define BATCH   8

typedef __attribute__((ext_vector_type(8))) __bf16 bf16x8;
typedef __attribute__((ext_vector_type(4))) float  f32x4;
typedef __attribute__((ext_vector_type(8))) unsigned short u16x8;

typedef const __attribute__((address_space(1))) void* gas1_t;
typedef __attribute__((address_space(3))) void*       las3_t;

__device__ __forceinline__ void stage16(const void* g, void* l) {
  __builtin_amdgcn_global_load_lds((gas1_t)g, (las3_t)l, 16, 0, 0);
}

__device__ __forceinline__ unsigned short f2bf(float f) {
  union { float f; uint32_t u; } v; v.f = f;
  uint32_t u = v.u;
  return (unsigned short)((u + 0x7FFFu + ((u >> 16) & 1u)) >> 16); // RTNE
}
__device__ __forceinline__ float bf2f(unsigned short u) {
  union { uint32_t u; float f; } v; v.u = ((uint32_t)u) << 16;
  return v.f;
}

// ---------------- k_pre: fused H/W bf16 casts + symmetrize+degree ----------------
__global__ __launch_bounds__(256) void k_pre(const float* __restrict__ A,
                                             unsigned short* __restrict__ Sb,
                                             float* __restrict__ D,
                                             const float4* __restrict__ H4,
                                             ushort4* __restrict__ Hb4,
                                             const float* __restrict__ W,
                                             unsigned short* __restrict__ Wt) {
  int t = threadIdx.x;
  int bid = blockIdx.y * 64 + blockIdx.x;
  // H cast: 2,097,152 float4 units, 512 per block
  {
    int i = bid * 512 + t;
    float4 v = H4[i];
    ushort4 o; o.x = f2bf(v.x); o.y = f2bf(v.y); o.z = f2bf(v.z); o.w = f2bf(v.w);
    Hb4[i] = o;
    i += 256;
    v = H4[i];
    o.x = f2bf(v.x); o.y = f2bf(v.y); o.z = f2bf(v.z); o.w = f2bf(v.w);
    Hb4[i] = o;
  }
  // W transpose-cast: blocks 0..255
  if (bid < 256) Wt[t * 256 + bid] = f2bf(W[bid * 256 + t]);

  int bi = blockIdx.y, bj = blockIdx.x;
  if (bj < bi) return;                 // upper-triangle blocks only
  __shared__ float L1[64][65];
  __shared__ float L2[64][65];
  __shared__ float Pr[4][64];
  __shared__ float Pc[4][64];
  int i0 = bi * 64, j0 = bj * 64;
  for (int it = 0; it < 16; ++it) {
    int idx = it * 256 + t;
    int r = idx >> 6, c = idx & 63;
    L1[r][c] = A[(size_t)(i0 + r) * N_NODES + (j0 + c)];
    L2[c][r] = A[(size_t)(j0 + r) * N_NODES + (i0 + c)];
  }
  __syncthreads();
  float colsum = 0.f;
  int cfix = t & 63, q = t >> 6;
  for (int it = 0; it < 16; ++it) {
    int r = it * 4 + q;
    float v = 0.5f * (L1[r][cfix] + L2[r][cfix]);
    v = v > 0.f ? v : 0.f;
    Sb[(size_t)(i0 + r) * N_NODES + (j0 + cfix)] = f2bf(v);
    colsum += v;
    L1[r][cfix] = v;
  }
  Pc[q][cfix] = colsum;
  __syncthreads();
  {
    int r = t & 63, seg = t >> 6;
    float s = 0.f;
    for (int c = seg * 16; c < seg * 16 + 16; ++c) s += L1[r][c];
    Pr[seg][r] = s;
  }
  __syncthreads();
  if (t < 64) {
    float d = Pr[0][t] + Pr[1][t] + Pr[2][t] + Pr[3][t];
    atomicAdd(&D[i0 + t], d);
  } else if (t < 128 && bi != bj) {
    int c = t - 64;
    float d = Pc[0][c] + Pc[1][c] + Pc[2][c] + Pc[3][c];
    atomicAdd(&D[j0 + c], d);
  }
  if (bi != bj) {
    for (int it = 0; it < 16; ++it) {
      int idx = it * 256 + t;
      int ro = idx >> 6, co = idx & 63;
      Sb[(size_t)(j0 + ro) * N_NODES + (i0 + co)] = f2bf(L1[co][ro]);
    }
  }
}

__global__ void k_dinv(const float* __restrict__ D, float* __restrict__ dinv) {
  int i = blockIdx.x * blockDim.x + threadIdx.x;
  if (i < N_NODES) {
    float d = D[i];
    dinv[i] = d > 0.f ? 1.0f / sqrtf(d) : 0.f;
  }
}

// ---------------- GEMM1: HW = Hb @ Wt^T; HWb (bf16) + Gt[b*256+o][n]=dinv[n]*HW ----
__global__ __launch_bounds__(256) void k_gemm1(const unsigned short* __restrict__ Hb,
                                               const unsigned short* __restrict__ Wt,
                                               const float* __restrict__ dinv,
                                               unsigned short* __restrict__ HWb,
                                               unsigned short* __restrict__ Gt) {
  __shared__ __align__(16) unsigned short As[128 * 32];
  __shared__ __align__(16) unsigned short Bs[128 * 32];
  __shared__ __align__(16) unsigned short T[128][136];
  int t = threadIdx.x;
  int lane = t & 63;
  int q = lane >> 4, r16 = lane & 15;
  int wave = t >> 6;
  int wm = wave >> 1, wn = wave & 1;
  int m0 = blockIdx.y * 128;
  int o0 = blockIdx.x * 128;
  const int K = 256;

  const unsigned short* Abase = Hb + (size_t)m0 * K;
  const unsigned short* Bbase = Wt + (size_t)o0 * K;

  f32x4 acc[4][4];
#pragma unroll
  for (int i = 0; i < 4; ++i)
#pragma unroll
    for (int j = 0; j < 4; ++j) acc[i][j] = f32x4{0.f, 0.f, 0.f, 0.f};

  int idx0 = t, idx1 = 256 + t;
  int wb0 = (t & ~63) * 8;
  int wb1 = (256 + (t & ~63)) * 8;

  for (int kt = 0; kt < K / 32; ++kt) {
    int kof = kt * 32;
    stage16(Abase + (size_t)(idx0 >> 2) * K + kof + ((idx0 & 3) << 3), &As[wb0]);
    stage16(Abase + (size_t)(idx1 >> 2) * K + kof + ((idx1 & 3) << 3), &As[wb1]);
    stage16(Bbase + (size_t)(idx0 >> 2) * K + kof + ((idx0 & 3) << 3), &Bs[wb0]);
    stage16(Bbase + (size_t)(idx1 >> 2) * K + kof + ((idx1 & 3) << 3), &Bs[wb1]);
    __syncthreads();
    bf16x8 a[4], b[4];
#pragma unroll
    for (int mi = 0; mi < 4; ++mi)
      a[mi] = *(const bf16x8*)&As[(wm * 64 + mi * 16 + r16) * 32 + q * 8];
#pragma unroll
    for (int ni = 0; ni < 4; ++ni)
      b[ni] = *(const bf16x8*)&Bs[(wn * 64 + ni * 16 + r16) * 32 + q * 8];
#pragma unroll
    for (int mi = 0; mi < 4; ++mi)
#pragma unroll
      for (int ni = 0; ni < 4; ++ni)
        acc[mi][ni] = __builtin_amdgcn_mfma_f32_16x16x32_bf16(a[mi], b[ni], acc[mi][ni], 0, 0, 0);
    __syncthreads();
  }

#pragma unroll
  for (int mi = 0; mi < 4; ++mi) {
    int row = wm * 64 + mi * 16 + q * 4;
#pragma unroll
    for (int ni = 0; ni < 4; ++ni) {
      int col = wn * 64 + ni * 16 + r16;
#pragma unroll
      for (int rr = 0; rr < 4; ++rr) {
        unsigned short h = f2bf(acc[mi][ni][rr]);
        HWb[(size_t)(m0 + row + rr) * F_DIM + (o0 + col)] = h;
        T[col][row + rr] = h;
      }
    }
  }
  __syncthreads();
  int b = m0 >> 12, n0 = m0 & 4095;
  for (int it = 0; it < 8; ++it) {
    int unit = it * 256 + t;
    int ro = unit >> 4;
    int cs = (unit & 15) * 8;
    u16x8 v = *(const u16x8*)&T[ro][cs];
    u16x8 w;
#pragma unroll
    for (int j = 0; j < 8; ++j)
      w[j] = f2bf(bf2f(v[j]) * dinv[n0 + cs + j]);
    *(u16x8*)&Gt[(size_t)(b * 256 + o0 + ro) * N_NODES + n0 + cs] = w;
  }
}

// ---------------- GEMM2: swizzled LDS (conflict-free), 64x128 wave tiles via
// k-parity split, single-buffer 2-barrier K-loop, fused epilogue ----------------
__global__ __launch_bounds__(256, 2) void k_gemm2(const unsigned short* __restrict__ Sb,
                                                  const unsigned short* __restrict__ Gt,
                                                  const unsigned short* __restrict__ HWb,
                                                  const float* __restrict__ dinv,
                                                  float* __restrict__ Out) {
  __shared__ __align__(16) unsigned short As[128 * 32];  // 8 KB
  __shared__ __align__(16) unsigned short Bs[128 * 32];  // 8 KB
  __shared__ float Red[64 * 130];                        // 33.3 KB reduction scratch
  const int K = N_NODES;
  int t = threadIdx.x;
  int lane = t & 63;
  int q = lane >> 4, r16 = lane & 15;
  int wave = t >> 6;
  int wm = wave >> 1;        // m-half: rows wm*64..+64
  int kz = wave & 1;         // k-parity: this wave consumes kt with kt&1==kz
  int m0 = blockIdx.y * 128;
  int n0 = blockIdx.x * 128;

  const unsigned short* Abase = Sb + (size_t)m0 * K;
  const unsigned short* Bbase = Gt + (size_t)n0 * K;

  f32x4 acc[4][8];
#pragma unroll
  for (int i = 0; i < 4; ++i)
#pragma unroll
    for (int j = 0; j < 8; ++j) acc[i][j] = f32x4{0.f, 0.f, 0.f, 0.f};

  // staging: unit u (16B) holds global (row=u>>2, q=(qs - (row>>1))&3), qs=u&3
  int u0 = t, u1 = 256 + t;
  int r0 = u0 >> 2, q0 = ((u0 & 3) - (r0 >> 1)) & 3;
  int r1 = u1 >> 2, q1 = ((u1 & 3) - (r1 >> 1)) & 3;
  const unsigned short* pa0 = Abase + (size_t)r0 * K + q0 * 8;
  const unsigned short* pa1 = Abase + (size_t)r1 * K + q1 * 8;
  const unsigned short* pb0 = Bbase + (size_t)r0 * K + q0 * 8;
  const unsigned short* pb1 = Bbase + (size_t)r1 * K + q1 * 8;
  int wb0 = (t & ~63) * 8;
  int wb1 = (256 + (t & ~63)) * 8;

  // frag read offsets (swizzled): row*32 + ((q + (row>>1))&3)*8
  int aoff[4], boff[8];
#pragma unroll
  for (int mi = 0; mi < 4; ++mi) {
    int row = wm * 64 + mi * 16 + r16;
    aoff[mi] = row * 32 + (((q + (row >> 1)) & 3) << 3);
  }
#pragma unroll
  for (int ni = 0; ni < 8; ++ni) {
    int row = ni * 16 + r16;
    boff[ni] = row * 32 + (((q + (row >> 1)) & 3) << 3);
  }

  for (int kt = 0; kt < K / 32; ++kt) {
    int kof = kt * 32;
    stage16(pa0 + kof, &As[wb0]);
    stage16(pa1 + kof, &As[wb1]);
    stage16(pb0 + kof, &Bs[wb0]);
    stage16(pb1 + kof, &Bs[wb1]);
    __syncthreads();
    if ((kt & 1) == kz) {
      bf16x8 a[4], b[8];
#pragma unroll
      for (int mi = 0; mi < 4; ++mi) a[mi] = *(const bf16x8*)&As[aoff[mi]];
#pragma unroll
      for (int ni = 0; ni < 8; ++ni) b[ni] = *(const bf16x8*)&Bs[boff[ni]];
#pragma unroll
      for (int mi = 0; mi < 4; ++mi)
#pragma unroll
        for (int ni = 0; ni < 8; ++ni)
          acc[mi][ni] = __builtin_amdgcn_mfma_f32_16x16x32_bf16(a[mi], b[ni], acc[mi][ni], 0, 0, 0);
    }
    __syncthreads();
  }

  // cross-kz reduction (per wm half) + fused epilogue
  for (int round = 0; round < 2; ++round) {
    if (wm == round && kz == 1) {
#pragma unroll
      for (int mi = 0; mi < 4; ++mi)
#pragma unroll
        for (int ni = 0; ni < 8; ++ni)
#pragma unroll
          for (int rr = 0; rr < 4; ++rr)
            Red[(mi * 16 + q * 4 + rr) * 130 + ni * 16 + r16] = acc[mi][ni][rr];
    }
    __syncthreads();
    if (wm == round && kz == 0) {
#pragma unroll
      for (int mi = 0; mi < 4; ++mi) {
        int row = m0 + wm * 64 + mi * 16 + q * 4;
        float di[4];
#pragma unroll
        for (int rr = 0; rr < 4; ++rr) di[rr] = dinv[row + rr];
#pragma unroll
        for (int ni = 0; ni < 8; ++ni) {
          int col = n0 + ni * 16 + r16;
          int b_ = col >> 8, o = col & 255;
#pragma unroll
          for (int rr = 0; rr < 4; ++rr) {
            float v = acc[mi][ni][rr] + Red[(mi * 16 + q * 4 + rr) * 130 + ni * 16 + r16];
            size_t oi = ((size_t)b_ * N_NODES + (row + rr)) * F_DIM + o;
            float u = bf2f(HWb[oi]) - di[rr] * v;
            Out[oi] = u > 0.f ? u : 0.f;
          }
        }
      }
    }
    __syncthreads();
  }
}

extern "C" void kernel_launch(void* const* d_in, const int* in_sizes, int n_in,
                              void* d_out, int out_size, void* d_ws, size_t ws_size,
                              hipStream_t stream) {
  (void)in_sizes; (void)n_in; (void)out_size; (void)ws_size;
  const float* H = (const float*)d_in[0];
  const float* W = (const float*)d_in[1];
  const float* A = (const float*)d_in[2];
  float* out = (float*)d_out;

  char* ws = (char*)d_ws;
  size_t off = 0;
  auto alloc = [&](size_t bytes) {
    char* p = ws + off;
    off += (bytes + 255) & ~(size_t)255;
    return p;
  };
  float*          Dd   = (float*)alloc((size_t)N_NODES * 4);
  float*          dinv = (float*)alloc((size_t)N_NODES * 4);
  unsigned short* Sb   = (unsigned short*)alloc((size_t)N_NODES * N_NODES * 2);        // 32 MB
  unsigned short* HWb  = (unsigned short*)alloc((size_t)BATCH * N_NODES * F_DIM * 2);  // 16 MB
  unsigned short* Gt   = (unsigned short*)alloc((size_t)BATCH * F_DIM * N_NODES * 2);  // 16 MB
  unsigned short* Wt   = (unsigned short*)alloc((size_t)F_DIM * F_DIM * 2);
  unsigned short* Hb   = (unsigned short*)alloc((size_t)BATCH * N_NODES * F_DIM * 2);  // 16 MB

  hipMemsetAsync(Dd, 0, N_NODES * 4, stream);
  k_pre<<<dim3(64, 64), 256, 0, stream>>>(A, Sb, Dd, (const float4*)H, (ushort4*)Hb, W, Wt);
  k_dinv<<<16, 256, 0, stream>>>(Dd, dinv);
  k_gemm1<<<dim3(2, 256), 256, 0, stream>>>(Hb, Wt, dinv, HWb, Gt);
  k_gemm2<<<dim3(16, 32), 256, 0, stream>>>(Sb, Gt, HWb, dinv, out);
}

// Round 5
// 256.749 us; speedup vs baseline: 1.1347x; 1.0127x over previous
//
#include <hip/hip_runtime.h>
#include <stdint.h>

#define N_NODES 4096
#define F_DIM   256
#define BATCH   8

typedef __attribute__((ext_vector_type(8))) __bf16 bf16x8;
typedef __attribute__((ext_vector_type(4))) float  f32x4;
typedef __attribute__((ext_vector_type(8))) unsigned short u16x8;

typedef const __attribute__((address_space(1))) void* gas1_t;
typedef __attribute__((address_space(3))) void*       las3_t;

__device__ __forceinline__ void stage16(const void* g, void* l) {
  __builtin_amdgcn_global_load_lds((gas1_t)g, (las3_t)l, 16, 0, 0);
}

__device__ __forceinline__ unsigned short f2bf(float f) {
  union { float f; uint32_t u; } v; v.f = f;
  uint32_t u = v.u;
  return (unsigned short)((u + 0x7FFFu + ((u >> 16) & 1u)) >> 16); // RTNE
}
__device__ __forceinline__ float bf2f(unsigned short u) {
  union { uint32_t u; float f; } v; v.u = ((uint32_t)u) << 16;
  return v.f;
}

// ---------------- k_pre: fused H/W bf16 casts + symmetrize+degree ----------------
__global__ __launch_bounds__(256) void k_pre(const float* __restrict__ A,
                                             unsigned short* __restrict__ Sb,
                                             float* __restrict__ D,
                                             const float4* __restrict__ H4,
                                             ushort4* __restrict__ Hb4,
                                             const float* __restrict__ W,
                                             unsigned short* __restrict__ Wt) {
  int t = threadIdx.x;
  int bid = blockIdx.y * 64 + blockIdx.x;
  {
    int i = bid * 512 + t;
    float4 v = H4[i];
    ushort4 o; o.x = f2bf(v.x); o.y = f2bf(v.y); o.z = f2bf(v.z); o.w = f2bf(v.w);
    Hb4[i] = o;
    i += 256;
    v = H4[i];
    o.x = f2bf(v.x); o.y = f2bf(v.y); o.z = f2bf(v.z); o.w = f2bf(v.w);
    Hb4[i] = o;
  }
  if (bid < 256) Wt[t * 256 + bid] = f2bf(W[bid * 256 + t]);

  int bi = blockIdx.y, bj = blockIdx.x;
  if (bj < bi) return;
  __shared__ float L1[64][65];
  __shared__ float L2[64][65];
  __shared__ float Pr[4][64];
  __shared__ float Pc[4][64];
  int i0 = bi * 64, j0 = bj * 64;
  for (int it = 0; it < 16; ++it) {
    int idx = it * 256 + t;
    int r = idx >> 6, c = idx & 63;
    L1[r][c] = A[(size_t)(i0 + r) * N_NODES + (j0 + c)];
    L2[c][r] = A[(size_t)(j0 + r) * N_NODES + (i0 + c)];
  }
  __syncthreads();
  float colsum = 0.f;
  int cfix = t & 63, q = t >> 6;
  for (int it = 0; it < 16; ++it) {
    int r = it * 4 + q;
    float v = 0.5f * (L1[r][cfix] + L2[r][cfix]);
    v = v > 0.f ? v : 0.f;
    Sb[(size_t)(i0 + r) * N_NODES + (j0 + cfix)] = f2bf(v);
    colsum += v;
    L1[r][cfix] = v;
  }
  Pc[q][cfix] = colsum;
  __syncthreads();
  {
    int r = t & 63, seg = t >> 6;
    float s = 0.f;
    for (int c = seg * 16; c < seg * 16 + 16; ++c) s += L1[r][c];
    Pr[seg][r] = s;
  }
  __syncthreads();
  if (t < 64) {
    float d = Pr[0][t] + Pr[1][t] + Pr[2][t] + Pr[3][t];
    atomicAdd(&D[i0 + t], d);
  } else if (t < 128 && bi != bj) {
    int c = t - 64;
    float d = Pc[0][c] + Pc[1][c] + Pc[2][c] + Pc[3][c];
    atomicAdd(&D[j0 + c], d);
  }
  if (bi != bj) {
    for (int it = 0; it < 16; ++it) {
      int idx = it * 256 + t;
      int ro = idx >> 6, co = idx & 63;
      Sb[(size_t)(j0 + ro) * N_NODES + (i0 + co)] = f2bf(L1[co][ro]);
    }
  }
}

__global__ void k_dinv(const float* __restrict__ D, float* __restrict__ dinv) {
  int i = blockIdx.x * blockDim.x + threadIdx.x;
  if (i < N_NODES) {
    float d = D[i];
    dinv[i] = d > 0.f ? 1.0f / sqrtf(d) : 0.f;
  }
}

// ---------------- GEMM1: HW = Hb @ Wt^T; HWb (bf16) + Gt[b*256+o][n]=dinv[n]*HW ----
__global__ __launch_bounds__(256) void k_gemm1(const unsigned short* __restrict__ Hb,
                                               const unsigned short* __restrict__ Wt,
                                               const float* __restrict__ dinv,
                                               unsigned short* __restrict__ HWb,
                                               unsigned short* __restrict__ Gt) {
  __shared__ __align__(16) unsigned short As[128 * 32];
  __shared__ __align__(16) unsigned short Bs[128 * 32];
  __shared__ __align__(16) unsigned short T[128][136];
  int t = threadIdx.x;
  int lane = t & 63;
  int q = lane >> 4, r16 = lane & 15;
  int wave = t >> 6;
  int wm = wave >> 1, wn = wave & 1;
  int m0 = blockIdx.y * 128;
  int o0 = blockIdx.x * 128;
  const int K = 256;

  const unsigned short* Abase = Hb + (size_t)m0 * K;
  const unsigned short* Bbase = Wt + (size_t)o0 * K;

  f32x4 acc[4][4];
#pragma unroll
  for (int i = 0; i < 4; ++i)
#pragma unroll
    for (int j = 0; j < 4; ++j) acc[i][j] = f32x4{0.f, 0.f, 0.f, 0.f};

  int idx0 = t, idx1 = 256 + t;
  int wb0 = (t & ~63) * 8;
  int wb1 = (256 + (t & ~63)) * 8;

  for (int kt = 0; kt < K / 32; ++kt) {
    int kof = kt * 32;
    stage16(Abase + (size_t)(idx0 >> 2) * K + kof + ((idx0 & 3) << 3), &As[wb0]);
    stage16(Abase + (size_t)(idx1 >> 2) * K + kof + ((idx1 & 3) << 3), &As[wb1]);
    stage16(Bbase + (size_t)(idx0 >> 2) * K + kof + ((idx0 & 3) << 3), &Bs[wb0]);
    stage16(Bbase + (size_t)(idx1 >> 2) * K + kof + ((idx1 & 3) << 3), &Bs[wb1]);
    __syncthreads();
    bf16x8 a[4], b[4];
#pragma unroll
    for (int mi = 0; mi < 4; ++mi)
      a[mi] = *(const bf16x8*)&As[(wm * 64 + mi * 16 + r16) * 32 + q * 8];
#pragma unroll
    for (int ni = 0; ni < 4; ++ni)
      b[ni] = *(const bf16x8*)&Bs[(wn * 64 + ni * 16 + r16) * 32 + q * 8];
#pragma unroll
    for (int mi = 0; mi < 4; ++mi)
#pragma unroll
      for (int ni = 0; ni < 4; ++ni)
        acc[mi][ni] = __builtin_amdgcn_mfma_f32_16x16x32_bf16(a[mi], b[ni], acc[mi][ni], 0, 0, 0);
    __syncthreads();
  }

#pragma unroll
  for (int mi = 0; mi < 4; ++mi) {
    int row = wm * 64 + mi * 16 + q * 4;
#pragma unroll
    for (int ni = 0; ni < 4; ++ni) {
      int col = wn * 64 + ni * 16 + r16;
#pragma unroll
      for (int rr = 0; rr < 4; ++rr) {
        unsigned short h = f2bf(acc[mi][ni][rr]);
        HWb[(size_t)(m0 + row + rr) * F_DIM + (o0 + col)] = h;
        T[col][row + rr] = h;
      }
    }
  }
  __syncthreads();
  int b = m0 >> 12, n0 = m0 & 4095;
  for (int it = 0; it < 8; ++it) {
    int unit = it * 256 + t;
    int ro = unit >> 4;
    int cs = (unit & 15) * 8;
    u16x8 v = *(const u16x8*)&T[ro][cs];
    u16x8 w;
#pragma unroll
    for (int j = 0; j < 8; ++j)
      w[j] = f2bf(bf2f(v[j]) * dinv[n0 + cs + j]);
    *(u16x8*)&Gt[(size_t)(b * 256 + o0 + ro) * N_NODES + n0 + cs] = w;
  }
}

// ---------------- GEMM2: round-4 kernel + XCD-patch block swizzle ----------------
// Linear bid -> XCD via bid%8 (round-robin dispatch). Each XCD owns an 8x8
// patch of (mt,nt) tiles; its 64 blocks stream k phase-aligned so the live
// k-window (~2 MB of Sb/Gt stripes) stays L2-resident -> L2 serves the 1 GB
// stream instead of L3.
__global__ __launch_bounds__(256, 2) void k_gemm2(const unsigned short* __restrict__ Sb,
                                                  const unsigned short* __restrict__ Gt,
                                                  const unsigned short* __restrict__ HWb,
                                                  const float* __restrict__ dinv,
                                                  float* __restrict__ Out) {
  __shared__ __align__(16) unsigned short As[128 * 32];
  __shared__ __align__(16) unsigned short Bs[128 * 32];
  __shared__ float Red[64 * 130];
  const int K = N_NODES;
  int t = threadIdx.x;
  int lane = t & 63;
  int q = lane >> 4, r16 = lane & 15;
  int wave = t >> 6;
  int wm = wave >> 1;
  int kz = wave & 1;

  // XCD-patch swizzle: grid (16,32) -> 512 linear ids, x-fastest
  int bid = blockIdx.y * 16 + blockIdx.x;
  int patch = bid & 7;          // -> XCD (round-robin assumption)
  int local = bid >> 3;         // 0..63 within patch
  int mt = (patch >> 1) * 8 + (local & 7);   // 0..31
  int nt = (patch & 1) * 8 + (local >> 3);   // 0..15
  int m0 = mt * 128;
  int n0 = nt * 128;

  const unsigned short* Abase = Sb + (size_t)m0 * K;
  const unsigned short* Bbase = Gt + (size_t)n0 * K;

  f32x4 acc[4][8];
#pragma unroll
  for (int i = 0; i < 4; ++i)
#pragma unroll
    for (int j = 0; j < 8; ++j) acc[i][j] = f32x4{0.f, 0.f, 0.f, 0.f};

  int u0 = t, u1 = 256 + t;
  int r0 = u0 >> 2, q0 = ((u0 & 3) - (r0 >> 1)) & 3;
  int r1 = u1 >> 2, q1 = ((u1 & 3) - (r1 >> 1)) & 3;
  const unsigned short* pa0 = Abase + (size_t)r0 * K + q0 * 8;
  const unsigned short* pa1 = Abase + (size_t)r1 * K + q1 * 8;
  const unsigned short* pb0 = Bbase + (size_t)r0 * K + q0 * 8;
  const unsigned short* pb1 = Bbase + (size_t)r1 * K + q1 * 8;
  int wb0 = (t & ~63) * 8;
  int wb1 = (256 + (t & ~63)) * 8;

  int aoff[4], boff[8];
#pragma unroll
  for (int mi = 0; mi < 4; ++mi) {
    int row = wm * 64 + mi * 16 + r16;
    aoff[mi] = row * 32 + (((q + (row >> 1)) & 3) << 3);
  }
#pragma unroll
  for (int ni = 0; ni < 8; ++ni) {
    int row = ni * 16 + r16;
    boff[ni] = row * 32 + (((q + (row >> 1)) & 3) << 3);
  }

  for (int kt = 0; kt < K / 32; ++kt) {
    int kof = kt * 32;
    stage16(pa0 + kof, &As[wb0]);
    stage16(pa1 + kof, &As[wb1]);
    stage16(pb0 + kof, &Bs[wb0]);
    stage16(pb1 + kof, &Bs[wb1]);
    __syncthreads();
    if ((kt & 1) == kz) {
      bf16x8 a[4], b[8];
#pragma unroll
      for (int mi = 0; mi < 4; ++mi) a[mi] = *(const bf16x8*)&As[aoff[mi]];
#pragma unroll
      for (int ni = 0; ni < 8; ++ni) b[ni] = *(const bf16x8*)&Bs[boff[ni]];
#pragma unroll
      for (int mi = 0; mi < 4; ++mi)
#pragma unroll
        for (int ni = 0; ni < 8; ++ni)
          acc[mi][ni] = __builtin_amdgcn_mfma_f32_16x16x32_bf16(a[mi], b[ni], acc[mi][ni], 0, 0, 0);
    }
    __syncthreads();
  }

  for (int round = 0; round < 2; ++round) {
    if (wm == round && kz == 1) {
#pragma unroll
      for (int mi = 0; mi < 4; ++mi)
#pragma unroll
        for (int ni = 0; ni < 8; ++ni)
#pragma unroll
          for (int rr = 0; rr < 4; ++rr)
            Red[(mi * 16 + q * 4 + rr) * 130 + ni * 16 + r16] = acc[mi][ni][rr];
    }
    __syncthreads();
    if (wm == round && kz == 0) {
#pragma unroll
      for (int mi = 0; mi < 4; ++mi) {
        int row = m0 + wm * 64 + mi * 16 + q * 4;
        float di[4];
#pragma unroll
        for (int rr = 0; rr < 4; ++rr) di[rr] = dinv[row + rr];
#pragma unroll
        for (int ni = 0; ni < 8; ++ni) {
          int col = n0 + ni * 16 + r16;
          int b_ = col >> 8, o = col & 255;
#pragma unroll
          for (int rr = 0; rr < 4; ++rr) {
            float v = acc[mi][ni][rr] + Red[(mi * 16 + q * 4 + rr) * 130 + ni * 16 + r16];
            size_t oi = ((size_t)b_ * N_NODES + (row + rr)) * F_DIM + o;
            float u = bf2f(HWb[oi]) - di[rr] * v;
            Out[oi] = u > 0.f ? u : 0.f;
          }
        }
      }
    }
    __syncthreads();
  }
}

extern "C" void kernel_launch(void* const* d_in, const int* in_sizes, int n_in,
                              void* d_out, int out_size, void* d_ws, size_t ws_size,
                              hipStream_t stream) {
  (void)in_sizes; (void)n_in; (void)out_size; (void)ws_size;
  const float* H = (const float*)d_in[0];
  const float* W = (const float*)d_in[1];
  const float* A = (const float*)d_in[2];
  float* out = (float*)d_out;

  char* ws = (char*)d_ws;
  size_t off = 0;
  auto alloc = [&](size_t bytes) {
    char* p = ws + off;
    off += (bytes + 255) & ~(size_t)255;
    return p;
  };
  float*          Dd   = (float*)alloc((size_t)N_NODES * 4);
  float*          dinv = (float*)alloc((size_t)N_NODES * 4);
  unsigned short* Sb   = (unsigned short*)alloc((size_t)N_NODES * N_NODES * 2);        // 32 MB
  unsigned short* HWb  = (unsigned short*)alloc((size_t)BATCH * N_NODES * F_DIM * 2);  // 16 MB
  unsigned short* Gt   = (unsigned short*)alloc((size_t)BATCH * F_DIM * N_NODES * 2);  // 16 MB
  unsigned short* Wt   = (unsigned short*)alloc((size_t)F_DIM * F_DIM * 2);
  unsigned short* Hb   = (unsigned short*)alloc((size_t)BATCH * N_NODES * F_DIM * 2);  // 16 MB

  hipMemsetAsync(Dd, 0, N_NODES * 4, stream);
  k_pre<<<dim3(64, 64), 256, 0, stream>>>(A, Sb, Dd, (const float4*)H, (ushort4*)Hb, W, Wt);
  k_dinv<<<16, 256, 0, stream>>>(Dd, dinv);
  k_gemm1<<<dim3(2, 256), 256, 0, stream>>>(Hb, Wt, dinv, HWb, Gt);
  k_gemm2<<<dim3(16, 32), 256, 0, stream>>>(Sb, Gt, HWb, dinv, out);
}